// Round 4
// baseline (199.845 us; speedup 1.0000x reference)
//
#include <hip/hip_runtime.h>

// Haar inverse DWT: out[b,c,2y+dy,2x+dx] from 4 subbands, each (8,64,256,256) f32.
// Pure streaming (1.074 GB once-touched), HBM-bound. Round 3 hit 5.74 TB/s (91%
// of 6.29 TB/s copy ceiling) with unit-stride b128 stores.
//
// Round 4: capped grid (2048 blocks = 8/CU) + grid-stride loop (16 iters/thread).
// Cuts workgroup dispatch count 16x and keeps the GPU's concurrent address
// window compact (~64 MB sweep per loop iteration, like the copy ubench);
// __restrict__ lets the compiler hoist next-iter loads above current stores.
//
// Mapping (unchanged from round 3): one wave per input row (256 floats).
//   lane l loads float2 j=l and j=64+l of the row from each subband.
//   Output row-pair base = row*1024 floats = float4 idx row*256:
//   lane l stores float4 idx base + {l, 64+l, 128+l, 192+l} — all four store
//   instructions lane-contiguous 16 B/lane (full cachelines), no shuffles.

using f32x2 = __attribute__((ext_vector_type(2))) float;
using f32x4 = __attribute__((ext_vector_type(4))) float;

__device__ __forceinline__ void haar_pair(const f32x2 a, const f32x2 b,
                                          const f32x2 c, const f32x2 d,
                                          f32x4& top, f32x4& bot)
{
    top[0] = 0.5f * (a[0] - b[0] - c[0] + d[0]);  // tl
    top[1] = 0.5f * (a[0] - b[0] + c[0] - d[0]);  // tr
    top[2] = 0.5f * (a[1] - b[1] - c[1] + d[1]);
    top[3] = 0.5f * (a[1] - b[1] + c[1] - d[1]);
    bot[0] = 0.5f * (a[0] + b[0] - c[0] - d[0]);  // bl
    bot[1] = 0.5f * (a[0] + b[0] + c[0] + d[0]);  // br
    bot[2] = 0.5f * (a[1] + b[1] - c[1] - d[1]);
    bot[3] = 0.5f * (a[1] + b[1] + c[1] + d[1]);
}

__global__ __launch_bounds__(256) void HaarIDWT_kernel(
    const float* __restrict__ ll, const float* __restrict__ lh,
    const float* __restrict__ hl, const float* __restrict__ hh,
    float* __restrict__ out, int nthreads)
{
    const int tid    = blockIdx.x * blockDim.x + threadIdx.x;
    const int stride = gridDim.x * blockDim.x;

    const f32x2* ll2 = reinterpret_cast<const f32x2*>(ll);
    const f32x2* lh2 = reinterpret_cast<const f32x2*>(lh);
    const f32x2* hl2 = reinterpret_cast<const f32x2*>(hl);
    const f32x2* hh2 = reinterpret_cast<const f32x2*>(hh);
    f32x4* out4 = reinterpret_cast<f32x4*>(out);

    for (int t = tid; t < nthreads; t += stride) {
        const int w = t >> 6;        // input row index
        const int l = t & 63;        // lane

        const int g1 = w * 128 + l;  // float2 index, first half of the row
        const int g2 = g1 + 64;      // second half

        const f32x2 a1 = ll2[g1], a2 = ll2[g2];
        const f32x2 b1 = lh2[g1], b2 = lh2[g2];
        const f32x2 c1 = hl2[g1], c2 = hl2[g2];
        const f32x2 d1 = hh2[g1], d2 = hh2[g2];

        f32x4 top1, bot1, top2, bot2;
        haar_pair(a1, b1, c1, d1, top1, bot1);
        haar_pair(a2, b2, c2, d2, top2, bot2);

        const int base = w * 256;    // float4 index of this row-pair's output
        out4[base +       l] = top1; // top row, first half
        out4[base +  64 + l] = top2; // top row, second half
        out4[base + 128 + l] = bot1; // bottom row, first half
        out4[base + 192 + l] = bot2; // bottom row, second half
    }
}

extern "C" void kernel_launch(void* const* d_in, const int* in_sizes, int n_in,
                              void* d_out, int out_size, void* d_ws, size_t ws_size,
                              hipStream_t stream) {
    const float* ll = (const float*)d_in[0];
    const float* lh = (const float*)d_in[1];
    const float* hl = (const float*)d_in[2];
    const float* hh = (const float*)d_in[3];
    float* out = (float*)d_out;

    const int n        = in_sizes[0];   // 8*64*256*256 = 33,554,432
    const int nthreads = n / 4;         // 8,388,608 (one per 4 input floats/subband)

    const int block = 256;
    const int grid  = 2048;             // 8 blocks/CU x 256 CU; 16 iters/thread
    HaarIDWT_kernel<<<grid, block, 0, stream>>>(ll, lh, hl, hh, out, nthreads);
}

// Round 5
// 192.988 us; speedup vs baseline: 1.0355x; 1.0355x over previous
//
#include <hip/hip_runtime.h>

// Haar inverse DWT: out[b,c,2y+dy,2x+dx] from 4 subbands, each (8,64,256,256) f32.
// Pure streaming (1.074 GB once-touched), HBM-bound.
// Round 3 (best, 187 us = 5.74 TB/s): 8B/lane loads (512 B/wave-instr) + unit-stride
// 16B/lane stores. Round 4 grid-stride regressed (200 us) - reverted.
//
// Round 5: test the last cell of the access-granularity matrix - 16B/lane
// CONTIGUOUS loads AND unit-stride stores, via a 16 KB LDS bounce per block.
//   Phase 1: block of 256 threads stages 4 input rows per subband:
//            thread tid loads float4 idx blk*256+tid from each subband
//            (1 KB contiguous per wave-instr, 4 KB contiguous per block per
//            subband = batched read bursts) -> sm4[sb][tid], sequential b128
//            LDS writes, conflict-free.
//   Phase 2: thread tid emits 4 unit-stride float4 stores:
//            out4[blk*1024 + k*256 + tid], k=0..3.  Local float idx 1024k+4*tid
//            -> row-pair k, top half if tid<128 (wave-uniform!), f4-col j=tid&127.
//            Needs input float2 j of local row k: sm2[sb*512 + k*128 + j]
//            (sequential b64 reads, conflict-free).
//   Signs: sb=-1 (top) / +1 (bottom):  u=a+sb*b, v=c+sb*d,
//          left=.5(u-v), right=.5(u+v)  ==  {tl,tr} / {bl,br}.

using f32x2 = __attribute__((ext_vector_type(2))) float;
using f32x4 = __attribute__((ext_vector_type(4))) float;

__global__ __launch_bounds__(256) void HaarIDWT_kernel(
    const float* __restrict__ ll, const float* __restrict__ lh,
    const float* __restrict__ hl, const float* __restrict__ hh,
    float* __restrict__ out)
{
    __shared__ f32x4 sm4[4][256];          // 16 KB: [subband][4 rows * 64 f32x4]

    const int tid = threadIdx.x;
    const int blk = blockIdx.x;
    const int gin = blk * 256 + tid;       // float4 index into each subband

    sm4[0][tid] = reinterpret_cast<const f32x4*>(ll)[gin];
    sm4[1][tid] = reinterpret_cast<const f32x4*>(lh)[gin];
    sm4[2][tid] = reinterpret_cast<const f32x4*>(hl)[gin];
    sm4[3][tid] = reinterpret_cast<const f32x4*>(hh)[gin];
    __syncthreads();

    const f32x2* sm2 = reinterpret_cast<const f32x2*>(&sm4[0][0]);
    const int   j  = tid & 127;                    // f4 col within output row
    const float sb = (tid < 128) ? -1.0f : 1.0f;   // top rows : bottom rows

    f32x4* out4 = reinterpret_cast<f32x4*>(out);
    const int obase = blk * 1024 + tid;

#pragma unroll
    for (int k = 0; k < 4; ++k) {                  // k = local input row
        const f32x2 A = sm2[0 * 512 + k * 128 + j];
        const f32x2 B = sm2[1 * 512 + k * 128 + j];
        const f32x2 C = sm2[2 * 512 + k * 128 + j];
        const f32x2 D = sm2[3 * 512 + k * 128 + j];

        const float u0 = fmaf(sb, B[0], A[0]);
        const float v0 = fmaf(sb, D[0], C[0]);
        const float u1 = fmaf(sb, B[1], A[1]);
        const float v1 = fmaf(sb, D[1], C[1]);

        f32x4 o;
        o[0] = 0.5f * (u0 - v0);
        o[1] = 0.5f * (u0 + v0);
        o[2] = 0.5f * (u1 - v1);
        o[3] = 0.5f * (u1 + v1);

        out4[obase + k * 256] = o;
    }
}

extern "C" void kernel_launch(void* const* d_in, const int* in_sizes, int n_in,
                              void* d_out, int out_size, void* d_ws, size_t ws_size,
                              hipStream_t stream) {
    const float* ll = (const float*)d_in[0];
    const float* lh = (const float*)d_in[1];
    const float* hl = (const float*)d_in[2];
    const float* hh = (const float*)d_in[3];
    float* out = (float*)d_out;

    const int n    = in_sizes[0];   // 8*64*256*256 = 33,554,432 floats per subband
    const int grid = n / 1024;      // 1024 floats (4 rows) per block -> 32768
    HaarIDWT_kernel<<<grid, 256, 0, stream>>>(ll, lh, hl, hh, out);
}

// Round 6
// 190.008 us; speedup vs baseline: 1.0518x; 1.0157x over previous
//
#include <hip/hip_runtime.h>

// Haar inverse DWT: out[b,c,2y+dy,2x+dx] from 4 subbands, each (8,64,256,256) f32.
// Pure streaming (1.074 GB once-touched), HBM-bound.
//
// FINAL (round-3 structure, 187 us = 5.74 TB/s = 91% of measured 6.29 TB/s
// 1R:1W copy ceiling). Measured matrix:
//   r1: 16B loads + 32B-stride stores        = 195 us
//   r2: + nontemporal hints                  = 226 us (nt hurts gfx950 write path)
//   r3: 8B loads + unit-stride 16B stores    = 187 us  <-- best
//   r4: r3 + capped-grid grid-stride         = 200 us (loop serializes MLP)
//   r5: 16B loads + unit stores via LDS      = 193 us (LDS cost > load-width gain)
// Residual ~9% vs copy ceiling = 5-stream mixed DRAM efficiency (structural).
//
// Mapping: one wave (64 lanes) per input row (256 floats = 128 float2).
//   lane l loads float2 idx l and 64+l of the row from each subband (8 B/lane;
//   each wave load instruction covers a contiguous 512 B segment).
//   Input float2 j (cols 2j,2j+1) -> output float4 j of top & bottom rows.
//   Output row-pair base = row*1024 floats = float4 idx row*256:
//   lane l stores float4 idx base + {l, 64+l, 128+l, 192+l} — all four store
//   instructions lane-contiguous 16 B/lane = 1 KB/instr (full cachelines),
//   no cross-lane exchange needed.
// Sign algebra kept in reference association order -> absmax 0.0.

using f32x2 = __attribute__((ext_vector_type(2))) float;
using f32x4 = __attribute__((ext_vector_type(4))) float;

__device__ __forceinline__ void haar_pair(const f32x2 a, const f32x2 b,
                                          const f32x2 c, const f32x2 d,
                                          f32x4& top, f32x4& bot)
{
    top[0] = 0.5f * (a[0] - b[0] - c[0] + d[0]);  // tl
    top[1] = 0.5f * (a[0] - b[0] + c[0] - d[0]);  // tr
    top[2] = 0.5f * (a[1] - b[1] - c[1] + d[1]);
    top[3] = 0.5f * (a[1] - b[1] + c[1] - d[1]);
    bot[0] = 0.5f * (a[0] + b[0] - c[0] - d[0]);  // bl
    bot[1] = 0.5f * (a[0] + b[0] + c[0] + d[0]);  // br
    bot[2] = 0.5f * (a[1] + b[1] - c[1] - d[1]);
    bot[3] = 0.5f * (a[1] + b[1] + c[1] + d[1]);
}

__global__ __launch_bounds__(256) void HaarIDWT_kernel(
    const float* __restrict__ ll, const float* __restrict__ lh,
    const float* __restrict__ hl, const float* __restrict__ hh,
    float* __restrict__ out, int nthreads)
{
    const int t = blockIdx.x * blockDim.x + threadIdx.x;
    if (t >= nthreads) return;

    const int w = t >> 6;        // wave id == input row index (8*64*256 rows)
    const int l = t & 63;        // lane

    const f32x2* ll2 = reinterpret_cast<const f32x2*>(ll);
    const f32x2* lh2 = reinterpret_cast<const f32x2*>(lh);
    const f32x2* hl2 = reinterpret_cast<const f32x2*>(hl);
    const f32x2* hh2 = reinterpret_cast<const f32x2*>(hh);

    const int g1 = w * 128 + l;      // float2 index, first half of the row
    const int g2 = g1 + 64;          // second half

    const f32x2 a1 = ll2[g1], a2 = ll2[g2];
    const f32x2 b1 = lh2[g1], b2 = lh2[g2];
    const f32x2 c1 = hl2[g1], c2 = hl2[g2];
    const f32x2 d1 = hh2[g1], d2 = hh2[g2];

    f32x4 top1, bot1, top2, bot2;
    haar_pair(a1, b1, c1, d1, top1, bot1);
    haar_pair(a2, b2, c2, d2, top2, bot2);

    f32x4* out4 = reinterpret_cast<f32x4*>(out);
    const int base = w * 256;        // float4 index of this row-pair's output
    out4[base +       l] = top1;     // top row, first half
    out4[base +  64 + l] = top2;     // top row, second half
    out4[base + 128 + l] = bot1;     // bottom row, first half
    out4[base + 192 + l] = bot2;     // bottom row, second half
}

extern "C" void kernel_launch(void* const* d_in, const int* in_sizes, int n_in,
                              void* d_out, int out_size, void* d_ws, size_t ws_size,
                              hipStream_t stream) {
    const float* ll = (const float*)d_in[0];
    const float* lh = (const float*)d_in[1];
    const float* hl = (const float*)d_in[2];
    const float* hh = (const float*)d_in[3];
    float* out = (float*)d_out;

    const int n        = in_sizes[0];   // 8*64*256*256 = 33,554,432
    const int nthreads = n / 4;         // one thread per 2 float2 per subband

    const int block = 256;
    const int grid  = (nthreads + block - 1) / block;   // 32768
    HaarIDWT_kernel<<<grid, block, 0, stream>>>(ll, lh, hl, hh, out, nthreads);
}